// Round 3
// baseline (85.021 us; speedup 1.0000x reference)
//
#include <hip/hip_runtime.h>

#define NN 8192
#define DD 64

typedef short bf16x8 __attribute__((ext_vector_type(8)));
typedef float f32x4 __attribute__((ext_vector_type(4)));

__device__ __forceinline__ unsigned short f2bf(float f) {
    unsigned int u = __float_as_uint(f);
    unsigned int r = (u + 0x7FFFu + ((u >> 16) & 1u)) >> 16;
    return (unsigned short)r;
}

// ---- Setup: X fp32 -> bf16 (RNE) into ws, plus per-row squared norms ----
__global__ __launch_bounds__(256) void rips_setup(const float* __restrict__ X,
                                                  unsigned short* __restrict__ Xb,
                                                  float* __restrict__ norms) {
    const int t   = blockIdx.x * 256 + threadIdx.x;
    const int row = t >> 3;
    const int j   = t & 7;
    const float* p = X + (size_t)row * DD + j * 8;
    float4 lo = *(const float4*)p;
    float4 hi = *(const float4*)(p + 4);

    bf16x8 v;
    v[0] = (short)f2bf(lo.x); v[1] = (short)f2bf(lo.y);
    v[2] = (short)f2bf(lo.z); v[3] = (short)f2bf(lo.w);
    v[4] = (short)f2bf(hi.x); v[5] = (short)f2bf(hi.y);
    v[6] = (short)f2bf(hi.z); v[7] = (short)f2bf(hi.w);
    *(bf16x8*)(Xb + (size_t)row * DD + j * 8) = v;

    float acc = lo.x*lo.x + lo.y*lo.y + lo.z*lo.z + lo.w*lo.w
              + hi.x*hi.x + hi.y*hi.y + hi.z*hi.z + hi.w*hi.w;
    acc += __shfl_xor(acc, 1);
    acc += __shfl_xor(acc, 2);
    acc += __shfl_xor(acc, 4);
    if (j == 0) norms[row] = acc;
}

// ---- Main: 128x128 tile per 256-thread block (4 waves, 2x2 of 64x64). ----
// A = column fragments, B = row fragments -> reg index walks 4 consecutive
// columns -> float4 nontemporal stores. XCD-chunked block swizzle: each XCD
// owns a contiguous 8-row-stripe band (1024 output rows), keeping its Xb row
// panel L2-hot and its write band contiguous.
__global__ __launch_bounds__(256) void rips_main(const unsigned short* __restrict__ Xb,
                                                 const float* __restrict__ norms,
                                                 float* __restrict__ out) {
    const int bid = blockIdx.x;
    const int swz = ((bid & 7) << 9) + (bid >> 3);   // 4096 blocks, 8 XCDs, bijective
    const int rowBase = (swz >> 6) * 128;
    const int colBase = (swz & 63) * 128;

    const int tid  = threadIdx.x;
    const int lane = tid & 63;
    const int w    = tid >> 6;
    const int wr   = w >> 1;
    const int wc   = w & 1;

    __shared__ float rn[128];
    __shared__ float cn[128];
    if (tid < 128) rn[tid]       = norms[rowBase + tid];
    else           cn[tid - 128] = norms[colBase + tid - 128];
    __syncthreads();

    const int fr = lane & 15;
    const int kg = lane >> 4;

    f32x4 acc[4][4];
    #pragma unroll
    for (int m = 0; m < 4; ++m)
        #pragma unroll
        for (int n = 0; n < 4; ++n)
            acc[m][n] = (f32x4){0.f, 0.f, 0.f, 0.f};

    #pragma unroll
    for (int kk = 0; kk < DD; kk += 32) {
        bf16x8 a[4], b[4];
        #pragma unroll
        for (int n = 0; n < 4; ++n)
            a[n] = *(const bf16x8*)(Xb + (size_t)(colBase + wc * 64 + n * 16 + fr) * DD + kk + kg * 8);
        #pragma unroll
        for (int m = 0; m < 4; ++m)
            b[m] = *(const bf16x8*)(Xb + (size_t)(rowBase + wr * 64 + m * 16 + fr) * DD + kk + kg * 8);
        #pragma unroll
        for (int m = 0; m < 4; ++m)
            #pragma unroll
            for (int n = 0; n < 4; ++n)
                acc[m][n] = __builtin_amdgcn_mfma_f32_16x16x32_bf16(a[n], b[m], acc[m][n], 0, 0, 0);
    }

    // Epilogue: lane holds row (fr) x 4 consecutive cols (kg*4..+3); nt stores.
    #pragma unroll
    for (int m = 0; m < 4; ++m) {
        const int row_l = wr * 64 + m * 16 + fr;
        const int grow  = rowBase + row_l;
        const float rnv = rn[row_l];
        #pragma unroll
        for (int n = 0; n < 4; ++n) {
            const int col0_l = wc * 64 + n * 16 + kg * 4;
            const int gcol0  = colBase + col0_l;
            const float4 cnv = *(const float4*)&cn[col0_l];
            f32x4 o;
            {
                float sq = fmaxf(rnv + cnv.x - 2.0f * acc[m][n][0], 0.0f);
                o[0] = (grow == gcol0 + 0) ? 0.0f : sqrtf(sq);
                sq = fmaxf(rnv + cnv.y - 2.0f * acc[m][n][1], 0.0f);
                o[1] = (grow == gcol0 + 1) ? 0.0f : sqrtf(sq);
                sq = fmaxf(rnv + cnv.z - 2.0f * acc[m][n][2], 0.0f);
                o[2] = (grow == gcol0 + 2) ? 0.0f : sqrtf(sq);
                sq = fmaxf(rnv + cnv.w - 2.0f * acc[m][n][3], 0.0f);
                o[3] = (grow == gcol0 + 3) ? 0.0f : sqrtf(sq);
            }
            __builtin_nontemporal_store(o, (f32x4*)(out + (size_t)grow * NN + gcol0));
        }
    }
}

// ---- Fallback (R1 kernel): used only if ws_size is too small ----
__global__ __launch_bounds__(256) void rips_fallback(const float* __restrict__ X,
                                                     float* __restrict__ out) {
    const int rowBase = blockIdx.y * 128;
    const int colBase = blockIdx.x * 128;
    const int tid  = threadIdx.x;
    const int lane = tid & 63;
    const int w    = tid >> 6;
    const int wr   = w >> 1;
    const int wc   = w & 1;

    __shared__ float rn[128];
    __shared__ float cn[128];
    {
        const int idx  = tid & 127;
        const int base = (tid < 128) ? rowBase : colBase;
        const float4* p = (const float4*)(X + (size_t)(base + idx) * DD);
        float acc = 0.0f;
        #pragma unroll
        for (int i = 0; i < 16; ++i) {
            float4 v = p[i];
            acc += v.x * v.x + v.y * v.y + v.z * v.z + v.w * v.w;
        }
        if (tid < 128) rn[idx] = acc;
        else           cn[idx] = acc;
    }
    __syncthreads();

    f32x4 acc[4][4];
    #pragma unroll
    for (int m = 0; m < 4; ++m)
        #pragma unroll
        for (int n = 0; n < 4; ++n)
            acc[m][n] = (f32x4){0.f, 0.f, 0.f, 0.f};

    const int fr = lane & 15;
    const int kg = lane >> 4;

    #pragma unroll
    for (int kk = 0; kk < DD; kk += 32) {
        bf16x8 a[4], b[4];
        #pragma unroll
        for (int m = 0; m < 4; ++m) {
            const float* p = X + (size_t)(rowBase + wr * 64 + m * 16 + fr) * DD + kk + kg * 8;
            float4 lo = *(const float4*)p;
            float4 hi = *(const float4*)(p + 4);
            bf16x8 t;
            t[0] = (short)f2bf(lo.x); t[1] = (short)f2bf(lo.y);
            t[2] = (short)f2bf(lo.z); t[3] = (short)f2bf(lo.w);
            t[4] = (short)f2bf(hi.x); t[5] = (short)f2bf(hi.y);
            t[6] = (short)f2bf(hi.z); t[7] = (short)f2bf(hi.w);
            a[m] = t;
        }
        #pragma unroll
        for (int n = 0; n < 4; ++n) {
            const float* p = X + (size_t)(colBase + wc * 64 + n * 16 + fr) * DD + kk + kg * 8;
            float4 lo = *(const float4*)p;
            float4 hi = *(const float4*)(p + 4);
            bf16x8 t;
            t[0] = (short)f2bf(lo.x); t[1] = (short)f2bf(lo.y);
            t[2] = (short)f2bf(lo.z); t[3] = (short)f2bf(lo.w);
            t[4] = (short)f2bf(hi.x); t[5] = (short)f2bf(hi.y);
            t[6] = (short)f2bf(hi.z); t[7] = (short)f2bf(hi.w);
            b[n] = t;
        }
        #pragma unroll
        for (int m = 0; m < 4; ++m)
            #pragma unroll
            for (int n = 0; n < 4; ++n)
                acc[m][n] = __builtin_amdgcn_mfma_f32_16x16x32_bf16(a[m], b[n], acc[m][n], 0, 0, 0);
    }

    #pragma unroll
    for (int m = 0; m < 4; ++m) {
        #pragma unroll
        for (int n = 0; n < 4; ++n) {
            #pragma unroll
            for (int r = 0; r < 4; ++r) {
                const int row_l = wr * 64 + m * 16 + kg * 4 + r;
                const int col_l = wc * 64 + n * 16 + fr;
                const float g  = acc[m][n][r];
                float sq = rn[row_l] + cn[col_l] - 2.0f * g;
                sq = fmaxf(sq, 0.0f);
                float dv = sqrtf(sq);
                const int grow = rowBase + row_l;
                const int gcol = colBase + col_l;
                if (grow == gcol) dv = 0.0f;
                out[(size_t)grow * NN + gcol] = dv;
            }
        }
    }
}

extern "C" void kernel_launch(void* const* d_in, const int* in_sizes, int n_in,
                              void* d_out, int out_size, void* d_ws, size_t ws_size,
                              hipStream_t stream) {
    const float* X = (const float*)d_in[0];
    float* out = (float*)d_out;

    const size_t xb_bytes   = (size_t)NN * DD * sizeof(unsigned short); // 1 MiB
    const size_t norm_bytes = (size_t)NN * sizeof(float);               // 32 KiB

    if (ws_size >= xb_bytes + norm_bytes) {
        unsigned short* Xb = (unsigned short*)d_ws;
        float* norms = (float*)((char*)d_ws + xb_bytes);
        rips_setup<<<dim3(NN * 8 / 256, 1, 1), dim3(256, 1, 1), 0, stream>>>(X, Xb, norms);
        rips_main<<<dim3(4096, 1, 1), dim3(256, 1, 1), 0, stream>>>(Xb, norms, out);
    } else {
        dim3 grid(NN / 128, NN / 128, 1);
        rips_fallback<<<grid, dim3(256, 1, 1), 0, stream>>>(X, out);
    }
}

// Round 4
// 66.490 us; speedup vs baseline: 1.2787x; 1.2787x over previous
//
#include <hip/hip_runtime.h>

#define NN 8192
#define DD 64

typedef short bf16x8 __attribute__((ext_vector_type(8)));
typedef float f32x4 __attribute__((ext_vector_type(4)));

__device__ __forceinline__ unsigned short f2bf(float f) {
    unsigned int u = __float_as_uint(f);
    unsigned int r = (u + 0x7FFFu + ((u >> 16) & 1u)) >> 16;
    return (unsigned short)r;
}

// ---- Setup: X fp32 -> bf16 (RNE) into ws, plus per-row squared norms ----
__global__ __launch_bounds__(256) void rips_setup(const float* __restrict__ X,
                                                  unsigned short* __restrict__ Xb,
                                                  float* __restrict__ norms) {
    const int t   = blockIdx.x * 256 + threadIdx.x;
    const int row = t >> 3;
    const int j   = t & 7;
    const float* p = X + (size_t)row * DD + j * 8;
    float4 lo = *(const float4*)p;
    float4 hi = *(const float4*)(p + 4);

    bf16x8 v;
    v[0] = (short)f2bf(lo.x); v[1] = (short)f2bf(lo.y);
    v[2] = (short)f2bf(lo.z); v[3] = (short)f2bf(lo.w);
    v[4] = (short)f2bf(hi.x); v[5] = (short)f2bf(hi.y);
    v[6] = (short)f2bf(hi.z); v[7] = (short)f2bf(hi.w);
    *(bf16x8*)(Xb + (size_t)row * DD + j * 8) = v;

    float acc = lo.x*lo.x + lo.y*lo.y + lo.z*lo.z + lo.w*lo.w
              + hi.x*hi.x + hi.y*hi.y + hi.z*hi.z + hi.w*hi.w;
    acc += __shfl_xor(acc, 1);
    acc += __shfl_xor(acc, 2);
    acc += __shfl_xor(acc, 4);
    if (j == 0) norms[row] = acc;
}

// ---- Main: 128x128 tile per 256-thread block (4 waves, 2x2 of 64x64). ----
// A = column fragments, B = row fragments -> reg index walks 4 consecutive
// columns -> float4 stores (normal, write-back cached: L2 merges the 64B
// chunks into full lines; nt stores regressed 34% in R3).
// XCD-chunked block swizzle (single change vs R2 for attribution).
__global__ __launch_bounds__(256) void rips_main(const unsigned short* __restrict__ Xb,
                                                 const float* __restrict__ norms,
                                                 float* __restrict__ out) {
    const int bid = blockIdx.x;
    const int swz = ((bid & 7) << 9) + (bid >> 3);   // 4096 blocks, 8 XCDs, bijective
    const int rowBase = (swz >> 6) * 128;
    const int colBase = (swz & 63) * 128;

    const int tid  = threadIdx.x;
    const int lane = tid & 63;
    const int w    = tid >> 6;
    const int wr   = w >> 1;
    const int wc   = w & 1;

    __shared__ float rn[128];
    __shared__ float cn[128];
    if (tid < 128) rn[tid]       = norms[rowBase + tid];
    else           cn[tid - 128] = norms[colBase + tid - 128];
    __syncthreads();

    const int fr = lane & 15;
    const int kg = lane >> 4;

    f32x4 acc[4][4];
    #pragma unroll
    for (int m = 0; m < 4; ++m)
        #pragma unroll
        for (int n = 0; n < 4; ++n)
            acc[m][n] = (f32x4){0.f, 0.f, 0.f, 0.f};

    #pragma unroll
    for (int kk = 0; kk < DD; kk += 32) {
        bf16x8 a[4], b[4];
        #pragma unroll
        for (int n = 0; n < 4; ++n)
            a[n] = *(const bf16x8*)(Xb + (size_t)(colBase + wc * 64 + n * 16 + fr) * DD + kk + kg * 8);
        #pragma unroll
        for (int m = 0; m < 4; ++m)
            b[m] = *(const bf16x8*)(Xb + (size_t)(rowBase + wr * 64 + m * 16 + fr) * DD + kk + kg * 8);
        #pragma unroll
        for (int m = 0; m < 4; ++m)
            #pragma unroll
            for (int n = 0; n < 4; ++n)
                acc[m][n] = __builtin_amdgcn_mfma_f32_16x16x32_bf16(a[n], b[m], acc[m][n], 0, 0, 0);
    }

    // Epilogue: lane holds row (fr) x 4 consecutive cols (kg*4..+3).
    #pragma unroll
    for (int m = 0; m < 4; ++m) {
        const int row_l = wr * 64 + m * 16 + fr;
        const int grow  = rowBase + row_l;
        const float rnv = rn[row_l];
        #pragma unroll
        for (int n = 0; n < 4; ++n) {
            const int col0_l = wc * 64 + n * 16 + kg * 4;
            const int gcol0  = colBase + col0_l;
            const float4 cnv = *(const float4*)&cn[col0_l];
            float4 o;
            {
                float sq = fmaxf(rnv + cnv.x - 2.0f * acc[m][n][0], 0.0f);
                o.x = (grow == gcol0 + 0) ? 0.0f : sqrtf(sq);
                sq = fmaxf(rnv + cnv.y - 2.0f * acc[m][n][1], 0.0f);
                o.y = (grow == gcol0 + 1) ? 0.0f : sqrtf(sq);
                sq = fmaxf(rnv + cnv.z - 2.0f * acc[m][n][2], 0.0f);
                o.z = (grow == gcol0 + 2) ? 0.0f : sqrtf(sq);
                sq = fmaxf(rnv + cnv.w - 2.0f * acc[m][n][3], 0.0f);
                o.w = (grow == gcol0 + 3) ? 0.0f : sqrtf(sq);
            }
            *(float4*)(out + (size_t)grow * NN + gcol0) = o;
        }
    }
}

// ---- Fallback (R1 kernel): used only if ws_size is too small ----
__global__ __launch_bounds__(256) void rips_fallback(const float* __restrict__ X,
                                                     float* __restrict__ out) {
    const int rowBase = blockIdx.y * 128;
    const int colBase = blockIdx.x * 128;
    const int tid  = threadIdx.x;
    const int lane = tid & 63;
    const int w    = tid >> 6;
    const int wr   = w >> 1;
    const int wc   = w & 1;

    __shared__ float rn[128];
    __shared__ float cn[128];
    {
        const int idx  = tid & 127;
        const int base = (tid < 128) ? rowBase : colBase;
        const float4* p = (const float4*)(X + (size_t)(base + idx) * DD);
        float acc = 0.0f;
        #pragma unroll
        for (int i = 0; i < 16; ++i) {
            float4 v = p[i];
            acc += v.x * v.x + v.y * v.y + v.z * v.z + v.w * v.w;
        }
        if (tid < 128) rn[idx] = acc;
        else           cn[idx] = acc;
    }
    __syncthreads();

    f32x4 acc[4][4];
    #pragma unroll
    for (int m = 0; m < 4; ++m)
        #pragma unroll
        for (int n = 0; n < 4; ++n)
            acc[m][n] = (f32x4){0.f, 0.f, 0.f, 0.f};

    const int fr = lane & 15;
    const int kg = lane >> 4;

    #pragma unroll
    for (int kk = 0; kk < DD; kk += 32) {
        bf16x8 a[4], b[4];
        #pragma unroll
        for (int m = 0; m < 4; ++m) {
            const float* p = X + (size_t)(rowBase + wr * 64 + m * 16 + fr) * DD + kk + kg * 8;
            float4 lo = *(const float4*)p;
            float4 hi = *(const float4*)(p + 4);
            bf16x8 t;
            t[0] = (short)f2bf(lo.x); t[1] = (short)f2bf(lo.y);
            t[2] = (short)f2bf(lo.z); t[3] = (short)f2bf(lo.w);
            t[4] = (short)f2bf(hi.x); t[5] = (short)f2bf(hi.y);
            t[6] = (short)f2bf(hi.z); t[7] = (short)f2bf(hi.w);
            a[m] = t;
        }
        #pragma unroll
        for (int n = 0; n < 4; ++n) {
            const float* p = X + (size_t)(colBase + wc * 64 + n * 16 + fr) * DD + kk + kg * 8;
            float4 lo = *(const float4*)p;
            float4 hi = *(const float4*)(p + 4);
            bf16x8 t;
            t[0] = (short)f2bf(lo.x); t[1] = (short)f2bf(lo.y);
            t[2] = (short)f2bf(lo.z); t[3] = (short)f2bf(lo.w);
            t[4] = (short)f2bf(hi.x); t[5] = (short)f2bf(hi.y);
            t[6] = (short)f2bf(hi.z); t[7] = (short)f2bf(hi.w);
            b[n] = t;
        }
        #pragma unroll
        for (int m = 0; m < 4; ++m)
            #pragma unroll
            for (int n = 0; n < 4; ++n)
                acc[m][n] = __builtin_amdgcn_mfma_f32_16x16x32_bf16(a[m], b[n], acc[m][n], 0, 0, 0);
    }

    #pragma unroll
    for (int m = 0; m < 4; ++m) {
        #pragma unroll
        for (int n = 0; n < 4; ++n) {
            #pragma unroll
            for (int r = 0; r < 4; ++r) {
                const int row_l = wr * 64 + m * 16 + kg * 4 + r;
                const int col_l = wc * 64 + n * 16 + fr;
                const float g  = acc[m][n][r];
                float sq = rn[row_l] + cn[col_l] - 2.0f * g;
                sq = fmaxf(sq, 0.0f);
                float dv = sqrtf(sq);
                const int grow = rowBase + row_l;
                const int gcol = colBase + col_l;
                if (grow == gcol) dv = 0.0f;
                out[(size_t)grow * NN + gcol] = dv;
            }
        }
    }
}

extern "C" void kernel_launch(void* const* d_in, const int* in_sizes, int n_in,
                              void* d_out, int out_size, void* d_ws, size_t ws_size,
                              hipStream_t stream) {
    const float* X = (const float*)d_in[0];
    float* out = (float*)d_out;

    const size_t xb_bytes   = (size_t)NN * DD * sizeof(unsigned short); // 1 MiB
    const size_t norm_bytes = (size_t)NN * sizeof(float);               // 32 KiB

    if (ws_size >= xb_bytes + norm_bytes) {
        unsigned short* Xb = (unsigned short*)d_ws;
        float* norms = (float*)((char*)d_ws + xb_bytes);
        rips_setup<<<dim3(NN * 8 / 256, 1, 1), dim3(256, 1, 1), 0, stream>>>(X, Xb, norms);
        rips_main<<<dim3(4096, 1, 1), dim3(256, 1, 1), 0, stream>>>(Xb, norms, out);
    } else {
        dim3 grid(NN / 128, NN / 128, 1);
        rips_fallback<<<grid, dim3(256, 1, 1), 0, stream>>>(X, out);
    }
}

// Round 5
// 62.555 us; speedup vs baseline: 1.3591x; 1.0629x over previous
//
#include <hip/hip_runtime.h>

#define NN 8192
#define DD 64

typedef short bf16x8 __attribute__((ext_vector_type(8)));
typedef float f32x4 __attribute__((ext_vector_type(4)));

__device__ __forceinline__ unsigned short f2bf(float f) {
    unsigned int u = __float_as_uint(f);
    unsigned int r = (u + 0x7FFFu + ((u >> 16) & 1u)) >> 16;
    return (unsigned short)r;
}

__device__ __forceinline__ float fsqrt(float x) {
#if __has_builtin(__builtin_amdgcn_sqrtf)
    return __builtin_amdgcn_sqrtf(x);
#else
    return sqrtf(x);
#endif
}

// ---- Setup: X fp32 -> bf16 (RNE) into ws, plus per-row squared norms ----
__global__ __launch_bounds__(256) void rips_setup(const float* __restrict__ X,
                                                  unsigned short* __restrict__ Xb,
                                                  float* __restrict__ norms) {
    const int t   = blockIdx.x * 256 + threadIdx.x;
    const int row = t >> 3;
    const int j   = t & 7;
    const float* p = X + (size_t)row * DD + j * 8;
    float4 lo = *(const float4*)p;
    float4 hi = *(const float4*)(p + 4);

    bf16x8 v;
    v[0] = (short)f2bf(lo.x); v[1] = (short)f2bf(lo.y);
    v[2] = (short)f2bf(lo.z); v[3] = (short)f2bf(lo.w);
    v[4] = (short)f2bf(hi.x); v[5] = (short)f2bf(hi.y);
    v[6] = (short)f2bf(hi.z); v[7] = (short)f2bf(hi.w);
    *(bf16x8*)(Xb + (size_t)row * DD + j * 8) = v;

    float acc = lo.x*lo.x + lo.y*lo.y + lo.z*lo.z + lo.w*lo.w
              + hi.x*hi.x + hi.y*hi.y + hi.z*hi.z + hi.w*hi.w;
    acc += __shfl_xor(acc, 1);
    acc += __shfl_xor(acc, 2);
    acc += __shfl_xor(acc, 4);
    if (j == 0) norms[row] = acc;
}

// ---- Main (symmetric): one block per lower-triangle 128x128 tile (r >= c).
// 2080 blocks. Off-diagonal blocks write the tile (float4) AND its transpose
// (scalar dwords; same 64B-segment geometry, L2 merges lines). MFMA/fetch/
// sqrt work halves vs the full-grid version; writes unchanged (the floor).
// Mirror values are bit-identical to direct computation (commutative adds).
__global__ __launch_bounds__(256) void rips_main_tri(const unsigned short* __restrict__ Xb,
                                                     const float* __restrict__ norms,
                                                     float* __restrict__ out) {
    const int b = blockIdx.x;
    int r = (int)((fsqrt(8.0f * (float)b + 1.0f) - 1.0f) * 0.5f);
    while ((r + 1) * (r + 2) / 2 <= b) ++r;
    while (r * (r + 1) / 2 > b) --r;
    const int c = b - r * (r + 1) / 2;
    const int rowBase = r * 128;
    const int colBase = c * 128;
    const bool isDiag = (r == c);

    const int tid  = threadIdx.x;
    const int lane = tid & 63;
    const int w    = tid >> 6;
    const int wr   = w >> 1;
    const int wc   = w & 1;

    __shared__ float rn[128];
    __shared__ float cn[128];
    if (tid < 128) rn[tid]       = norms[rowBase + tid];
    else           cn[tid - 128] = norms[colBase + tid - 128];
    __syncthreads();

    const int fr = lane & 15;
    const int kg = lane >> 4;

    f32x4 acc[4][4];
    #pragma unroll
    for (int m = 0; m < 4; ++m)
        #pragma unroll
        for (int n = 0; n < 4; ++n)
            acc[m][n] = (f32x4){0.f, 0.f, 0.f, 0.f};

    #pragma unroll
    for (int kk = 0; kk < DD; kk += 32) {
        bf16x8 a[4], bfr[4];
        #pragma unroll
        for (int n = 0; n < 4; ++n)
            a[n] = *(const bf16x8*)(Xb + (size_t)(colBase + wc * 64 + n * 16 + fr) * DD + kk + kg * 8);
        #pragma unroll
        for (int m = 0; m < 4; ++m)
            bfr[m] = *(const bf16x8*)(Xb + (size_t)(rowBase + wr * 64 + m * 16 + fr) * DD + kk + kg * 8);
        #pragma unroll
        for (int m = 0; m < 4; ++m)
            #pragma unroll
            for (int n = 0; n < 4; ++n)
                acc[m][n] = __builtin_amdgcn_mfma_f32_16x16x32_bf16(a[n], bfr[m], acc[m][n], 0, 0, 0);
    }

    // Epilogue: lane holds row (fr) x 4 consecutive cols (kg*4..+3).
    #pragma unroll
    for (int m = 0; m < 4; ++m) {
        const int row_l = wr * 64 + m * 16 + fr;
        const int grow  = rowBase + row_l;
        const float rnv = rn[row_l];
        #pragma unroll
        for (int n = 0; n < 4; ++n) {
            const int col0_l = wc * 64 + n * 16 + kg * 4;
            const int gcol0  = colBase + col0_l;
            const float4 cnv = *(const float4*)&cn[col0_l];
            float4 o;
            o.x = fsqrt(fmaxf(rnv + cnv.x - 2.0f * acc[m][n][0], 0.0f));
            o.y = fsqrt(fmaxf(rnv + cnv.y - 2.0f * acc[m][n][1], 0.0f));
            o.z = fsqrt(fmaxf(rnv + cnv.z - 2.0f * acc[m][n][2], 0.0f));
            o.w = fsqrt(fmaxf(rnv + cnv.w - 2.0f * acc[m][n][3], 0.0f));
            if (isDiag) {
                if (grow == gcol0 + 0) o.x = 0.0f;
                if (grow == gcol0 + 1) o.y = 0.0f;
                if (grow == gcol0 + 2) o.z = 0.0f;
                if (grow == gcol0 + 3) o.w = 0.0f;
            }
            *(float4*)(out + (size_t)grow * NN + gcol0) = o;
            if (!isDiag) {
                out[(size_t)(gcol0 + 0) * NN + grow] = o.x;
                out[(size_t)(gcol0 + 1) * NN + grow] = o.y;
                out[(size_t)(gcol0 + 2) * NN + grow] = o.z;
                out[(size_t)(gcol0 + 3) * NN + grow] = o.w;
            }
        }
    }
}

// ---- Fallback (R1 kernel): used only if ws_size is too small ----
__global__ __launch_bounds__(256) void rips_fallback(const float* __restrict__ X,
                                                     float* __restrict__ out) {
    const int rowBase = blockIdx.y * 128;
    const int colBase = blockIdx.x * 128;
    const int tid  = threadIdx.x;
    const int lane = tid & 63;
    const int w    = tid >> 6;
    const int wr   = w >> 1;
    const int wc   = w & 1;

    __shared__ float rn[128];
    __shared__ float cn[128];
    {
        const int idx  = tid & 127;
        const int base = (tid < 128) ? rowBase : colBase;
        const float4* p = (const float4*)(X + (size_t)(base + idx) * DD);
        float acc = 0.0f;
        #pragma unroll
        for (int i = 0; i < 16; ++i) {
            float4 v = p[i];
            acc += v.x * v.x + v.y * v.y + v.z * v.z + v.w * v.w;
        }
        if (tid < 128) rn[idx] = acc;
        else           cn[idx] = acc;
    }
    __syncthreads();

    f32x4 acc[4][4];
    #pragma unroll
    for (int m = 0; m < 4; ++m)
        #pragma unroll
        for (int n = 0; n < 4; ++n)
            acc[m][n] = (f32x4){0.f, 0.f, 0.f, 0.f};

    const int fr = lane & 15;
    const int kg = lane >> 4;

    #pragma unroll
    for (int kk = 0; kk < DD; kk += 32) {
        bf16x8 a[4], b[4];
        #pragma unroll
        for (int m = 0; m < 4; ++m) {
            const float* p = X + (size_t)(rowBase + wr * 64 + m * 16 + fr) * DD + kk + kg * 8;
            float4 lo = *(const float4*)p;
            float4 hi = *(const float4*)(p + 4);
            bf16x8 t;
            t[0] = (short)f2bf(lo.x); t[1] = (short)f2bf(lo.y);
            t[2] = (short)f2bf(lo.z); t[3] = (short)f2bf(lo.w);
            t[4] = (short)f2bf(hi.x); t[5] = (short)f2bf(hi.y);
            t[6] = (short)f2bf(hi.z); t[7] = (short)f2bf(hi.w);
            a[m] = t;
        }
        #pragma unroll
        for (int n = 0; n < 4; ++n) {
            const float* p = X + (size_t)(colBase + wc * 64 + n * 16 + fr) * DD + kk + kg * 8;
            float4 lo = *(const float4*)p;
            float4 hi = *(const float4*)(p + 4);
            bf16x8 t;
            t[0] = (short)f2bf(lo.x); t[1] = (short)f2bf(lo.y);
            t[2] = (short)f2bf(lo.z); t[3] = (short)f2bf(lo.w);
            t[4] = (short)f2bf(hi.x); t[5] = (short)f2bf(hi.y);
            t[6] = (short)f2bf(hi.z); t[7] = (short)f2bf(hi.w);
            b[n] = t;
        }
        #pragma unroll
        for (int m = 0; m < 4; ++m)
            #pragma unroll
            for (int n = 0; n < 4; ++n)
                acc[m][n] = __builtin_amdgcn_mfma_f32_16x16x32_bf16(a[m], b[n], acc[m][n], 0, 0, 0);
    }

    #pragma unroll
    for (int m = 0; m < 4; ++m) {
        #pragma unroll
        for (int n = 0; n < 4; ++n) {
            #pragma unroll
            for (int r = 0; r < 4; ++r) {
                const int row_l = wr * 64 + m * 16 + kg * 4 + r;
                const int col_l = wc * 64 + n * 16 + fr;
                const float g  = acc[m][n][r];
                float sq = rn[row_l] + cn[col_l] - 2.0f * g;
                sq = fmaxf(sq, 0.0f);
                float dv = sqrtf(sq);
                const int grow = rowBase + row_l;
                const int gcol = colBase + col_l;
                if (grow == gcol) dv = 0.0f;
                out[(size_t)grow * NN + gcol] = dv;
            }
        }
    }
}

extern "C" void kernel_launch(void* const* d_in, const int* in_sizes, int n_in,
                              void* d_out, int out_size, void* d_ws, size_t ws_size,
                              hipStream_t stream) {
    const float* X = (const float*)d_in[0];
    float* out = (float*)d_out;

    const size_t xb_bytes   = (size_t)NN * DD * sizeof(unsigned short); // 1 MiB
    const size_t norm_bytes = (size_t)NN * sizeof(float);               // 32 KiB

    if (ws_size >= xb_bytes + norm_bytes) {
        unsigned short* Xb = (unsigned short*)d_ws;
        float* norms = (float*)((char*)d_ws + xb_bytes);
        rips_setup<<<dim3(NN * 8 / 256, 1, 1), dim3(256, 1, 1), 0, stream>>>(X, Xb, norms);
        const int ntiles = NN / 128;                       // 64
        const int nblocks = ntiles * (ntiles + 1) / 2;     // 2080
        rips_main_tri<<<dim3(nblocks, 1, 1), dim3(256, 1, 1), 0, stream>>>(Xb, norms, out);
    } else {
        dim3 grid(NN / 128, NN / 128, 1);
        rips_fallback<<<grid, dim3(256, 1, 1), 0, stream>>>(X, out);
    }
}

// Round 6
// 56.385 us; speedup vs baseline: 1.5079x; 1.1094x over previous
//
#include <hip/hip_runtime.h>

#define NN 8192
#define DD 64

typedef short bf16x8 __attribute__((ext_vector_type(8)));
typedef float f32x4 __attribute__((ext_vector_type(4)));

__device__ __forceinline__ unsigned short f2bf(float f) {
    unsigned int u = __float_as_uint(f);
    unsigned int r = (u + 0x7FFFu + ((u >> 16) & 1u)) >> 16;
    return (unsigned short)r;
}

__device__ __forceinline__ float fsqrt(float x) {
#if __has_builtin(__builtin_amdgcn_sqrtf)
    return __builtin_amdgcn_sqrtf(x);
#else
    return sqrtf(x);
#endif
}

// ---- Setup: X fp32 -> bf16 (RNE) into ws, plus per-row squared norms ----
__global__ __launch_bounds__(256) void rips_setup(const float* __restrict__ X,
                                                  unsigned short* __restrict__ Xb,
                                                  float* __restrict__ norms) {
    const int t   = blockIdx.x * 256 + threadIdx.x;
    const int row = t >> 3;
    const int j   = t & 7;
    const float* p = X + (size_t)row * DD + j * 8;
    float4 lo = *(const float4*)p;
    float4 hi = *(const float4*)(p + 4);

    bf16x8 v;
    v[0] = (short)f2bf(lo.x); v[1] = (short)f2bf(lo.y);
    v[2] = (short)f2bf(lo.z); v[3] = (short)f2bf(lo.w);
    v[4] = (short)f2bf(hi.x); v[5] = (short)f2bf(hi.y);
    v[6] = (short)f2bf(hi.z); v[7] = (short)f2bf(hi.w);
    *(bf16x8*)(Xb + (size_t)row * DD + j * 8) = v;

    float acc = lo.x*lo.x + lo.y*lo.y + lo.z*lo.z + lo.w*lo.w
              + hi.x*hi.x + hi.y*hi.y + hi.z*hi.z + hi.w*hi.w;
    acc += __shfl_xor(acc, 1);
    acc += __shfl_xor(acc, 2);
    acc += __shfl_xor(acc, 4);
    if (j == 0) norms[row] = acc;
}

// ---- Main: 128x128 tile per block (4 waves, 2x2 of 64x64), R2 structure. ----
// Single change vs R2: epilogue staged through per-wave LDS so each global
// store instruction writes 4 rows x 256B contiguous (full 128B lines),
// instead of 16 rows x 64B (half-line transactions, theory H for the
// 4.3-vs-7.0 TB/s write gap).
// LDS stage stride = 72 floats: write phase 4-way conflict (cheap),
// read phase 2-way (free).
__global__ __launch_bounds__(256) void rips_main(const unsigned short* __restrict__ Xb,
                                                 const float* __restrict__ norms,
                                                 float* __restrict__ out) {
    const int bid = blockIdx.x;
    const int rowBase = (bid >> 6) * 128;   // consecutive bids advance cols (R2 order)
    const int colBase = (bid & 63) * 128;

    const int tid  = threadIdx.x;
    const int lane = tid & 63;
    const int w    = tid >> 6;
    const int wr   = w >> 1;
    const int wc   = w & 1;

    __shared__ float rn[128];
    __shared__ float cn[128];
    __shared__ float stage[4][16 * 72];     // per-wave 16-row x 64-col slice, stride 72

    if (tid < 128) rn[tid]       = norms[rowBase + tid];
    else           cn[tid - 128] = norms[colBase + tid - 128];
    __syncthreads();

    const int fr = lane & 15;
    const int kg = lane >> 4;

    f32x4 acc[4][4];
    #pragma unroll
    for (int m = 0; m < 4; ++m)
        #pragma unroll
        for (int n = 0; n < 4; ++n)
            acc[m][n] = (f32x4){0.f, 0.f, 0.f, 0.f};

    #pragma unroll
    for (int kk = 0; kk < DD; kk += 32) {
        bf16x8 a[4], bfr[4];
        #pragma unroll
        for (int n = 0; n < 4; ++n)
            a[n] = *(const bf16x8*)(Xb + (size_t)(colBase + wc * 64 + n * 16 + fr) * DD + kk + kg * 8);
        #pragma unroll
        for (int m = 0; m < 4; ++m)
            bfr[m] = *(const bf16x8*)(Xb + (size_t)(rowBase + wr * 64 + m * 16 + fr) * DD + kk + kg * 8);
        #pragma unroll
        for (int m = 0; m < 4; ++m)
            #pragma unroll
            for (int n = 0; n < 4; ++n)
                acc[m][n] = __builtin_amdgcn_mfma_f32_16x16x32_bf16(a[n], bfr[m], acc[m][n], 0, 0, 0);
    }

    // Epilogue per m-slice: compute -> LDS stage -> contiguous streaming store.
    float* st = stage[w];
    const int lr = lane >> 4;   // 0..3  (streaming row within group of 4)
    const int lc = lane & 15;   // 0..15 (streaming col group, 16B each)

    #pragma unroll
    for (int m = 0; m < 4; ++m) {
        const int row_l = wr * 64 + m * 16 + fr;
        const int grow  = rowBase + row_l;
        const float rnv = rn[row_l];
        #pragma unroll
        for (int n = 0; n < 4; ++n) {
            const int col0_l = wc * 64 + n * 16 + kg * 4;
            const int gcol0  = colBase + col0_l;
            const float4 cnv = *(const float4*)&cn[col0_l];
            f32x4 o;
            o[0] = fsqrt(fmaxf(rnv + cnv.x - 2.0f * acc[m][n][0], 0.0f));
            o[1] = fsqrt(fmaxf(rnv + cnv.y - 2.0f * acc[m][n][1], 0.0f));
            o[2] = fsqrt(fmaxf(rnv + cnv.z - 2.0f * acc[m][n][2], 0.0f));
            o[3] = fsqrt(fmaxf(rnv + cnv.w - 2.0f * acc[m][n][3], 0.0f));
            if (grow == gcol0 + 0) o[0] = 0.0f;
            if (grow == gcol0 + 1) o[1] = 0.0f;
            if (grow == gcol0 + 2) o[2] = 0.0f;
            if (grow == gcol0 + 3) o[3] = 0.0f;
            // LDS: local row fr (0..15), local col n*16 + kg*4
            *(f32x4*)&st[fr * 72 + n * 16 + kg * 4] = o;
        }
        // Stream this 16x64 slice: 4 insts, each 4 rows x 256B contiguous.
        #pragma unroll
        for (int t = 0; t < 4; ++t) {
            const int R = t * 4 + lr;                       // 0..15
            f32x4 v = *(const f32x4*)&st[R * 72 + lc * 4];
            const int srow = rowBase + wr * 64 + m * 16 + R;
            const int scol = colBase + wc * 64 + lc * 4;
            *(f32x4*)(out + (size_t)srow * NN + scol) = v;
        }
    }
}

// ---- Fallback (R1 kernel): used only if ws_size is too small ----
__global__ __launch_bounds__(256) void rips_fallback(const float* __restrict__ X,
                                                     float* __restrict__ out) {
    const int rowBase = blockIdx.y * 128;
    const int colBase = blockIdx.x * 128;
    const int tid  = threadIdx.x;
    const int lane = tid & 63;
    const int w    = tid >> 6;
    const int wr   = w >> 1;
    const int wc   = w & 1;

    __shared__ float rn[128];
    __shared__ float cn[128];
    {
        const int idx  = tid & 127;
        const int base = (tid < 128) ? rowBase : colBase;
        const float4* p = (const float4*)(X + (size_t)(base + idx) * DD);
        float acc = 0.0f;
        #pragma unroll
        for (int i = 0; i < 16; ++i) {
            float4 v = p[i];
            acc += v.x * v.x + v.y * v.y + v.z * v.z + v.w * v.w;
        }
        if (tid < 128) rn[idx] = acc;
        else           cn[idx] = acc;
    }
    __syncthreads();

    f32x4 acc[4][4];
    #pragma unroll
    for (int m = 0; m < 4; ++m)
        #pragma unroll
        for (int n = 0; n < 4; ++n)
            acc[m][n] = (f32x4){0.f, 0.f, 0.f, 0.f};

    const int fr = lane & 15;
    const int kg = lane >> 4;

    #pragma unroll
    for (int kk = 0; kk < DD; kk += 32) {
        bf16x8 a[4], b[4];
        #pragma unroll
        for (int m = 0; m < 4; ++m) {
            const float* p = X + (size_t)(rowBase + wr * 64 + m * 16 + fr) * DD + kk + kg * 8;
            float4 lo = *(const float4*)p;
            float4 hi = *(const float4*)(p + 4);
            bf16x8 t;
            t[0] = (short)f2bf(lo.x); t[1] = (short)f2bf(lo.y);
            t[2] = (short)f2bf(lo.z); t[3] = (short)f2bf(lo.w);
            t[4] = (short)f2bf(hi.x); t[5] = (short)f2bf(hi.y);
            t[6] = (short)f2bf(hi.z); t[7] = (short)f2bf(hi.w);
            a[m] = t;
        }
        #pragma unroll
        for (int n = 0; n < 4; ++n) {
            const float* p = X + (size_t)(colBase + wc * 64 + n * 16 + fr) * DD + kk + kg * 8;
            float4 lo = *(const float4*)p;
            float4 hi = *(const float4*)(p + 4);
            bf16x8 t;
            t[0] = (short)f2bf(lo.x); t[1] = (short)f2bf(lo.y);
            t[2] = (short)f2bf(lo.z); t[3] = (short)f2bf(lo.w);
            t[4] = (short)f2bf(hi.x); t[5] = (short)f2bf(hi.y);
            t[6] = (short)f2bf(hi.z); t[7] = (short)f2bf(hi.w);
            b[n] = t;
        }
        #pragma unroll
        for (int m = 0; m < 4; ++m)
            #pragma unroll
            for (int n = 0; n < 4; ++n)
                acc[m][n] = __builtin_amdgcn_mfma_f32_16x16x32_bf16(a[m], b[n], acc[m][n], 0, 0, 0);
    }

    #pragma unroll
    for (int m = 0; m < 4; ++m) {
        #pragma unroll
        for (int n = 0; n < 4; ++n) {
            #pragma unroll
            for (int r = 0; r < 4; ++r) {
                const int row_l = wr * 64 + m * 16 + kg * 4 + r;
                const int col_l = wc * 64 + n * 16 + fr;
                const float g  = acc[m][n][r];
                float sq = rn[row_l] + cn[col_l] - 2.0f * g;
                sq = fmaxf(sq, 0.0f);
                float dv = sqrtf(sq);
                const int grow = rowBase + row_l;
                const int gcol = colBase + col_l;
                if (grow == gcol) dv = 0.0f;
                out[(size_t)grow * NN + gcol] = dv;
            }
        }
    }
}

extern "C" void kernel_launch(void* const* d_in, const int* in_sizes, int n_in,
                              void* d_out, int out_size, void* d_ws, size_t ws_size,
                              hipStream_t stream) {
    const float* X = (const float*)d_in[0];
    float* out = (float*)d_out;

    const size_t xb_bytes   = (size_t)NN * DD * sizeof(unsigned short); // 1 MiB
    const size_t norm_bytes = (size_t)NN * sizeof(float);               // 32 KiB

    if (ws_size >= xb_bytes + norm_bytes) {
        unsigned short* Xb = (unsigned short*)d_ws;
        float* norms = (float*)((char*)d_ws + xb_bytes);
        rips_setup<<<dim3(NN * 8 / 256, 1, 1), dim3(256, 1, 1), 0, stream>>>(X, Xb, norms);
        rips_main<<<dim3(4096, 1, 1), dim3(256, 1, 1), 0, stream>>>(Xb, norms, out);
    } else {
        dim3 grid(NN / 128, NN / 128, 1);
        rips_fallback<<<grid, dim3(256, 1, 1), 0, stream>>>(X, out);
    }
}